// Round 2
// baseline (115.038 us; speedup 1.0000x reference)
//
#include <hip/hip_runtime.h>

// Problem: B=2, DEC=ENC=512, H=256.
// dec:(2,512,256) enc:(2,512,256) W:(256,512) b_mlp:(256) w_out:(1,256) b_out:(1)
// dec_proj[r][d] = sum_h dec[r][h]*W[d][256+h]
// enc_projb[r][d] = sum_h enc[r][h]*W[d][h] + b_mlp[d]
// attn[b,q,e] = sum_h relu(dp[bq][h]+epb[be][h]) * w[h] + b_out

// ---------------- Kernel 1: fused projections (A · W^T) ----------------
// C rows 0..1023 = dec rows (koff=256), rows 1024..2047 = enc rows (koff=0, +bias)
// Tile: TM=64 rows x TN=32 cols, TK=64. 128 threads, 4x4 per thread.
#define TK 64

__global__ __launch_bounds__(128) void proj_kernel(
    const float* __restrict__ dec, const float* __restrict__ enc,
    const float* __restrict__ W, const float* __restrict__ bmlp,
    float* __restrict__ dp, float* __restrict__ epb)
{
    __shared__ float As[64][TK + 4];  // stride 68 floats: 16B-aligned rows, conflict-free reads
    __shared__ float Ws[32][TK + 4];

    const int tid = threadIdx.x;       // 0..127
    const int tx = tid & 7;            // 0..7  (col groups)
    const int ty = tid >> 3;           // 0..15 (row groups)
    const int rowTile = blockIdx.y;    // 0..31 (rows rowTile*64)
    const int colTile = blockIdx.x;    // 0..7  (d = colTile*32)
    const bool isEnc = rowTile >= 16;
    const float* __restrict__ A = isEnc ? enc : dec;
    const int arow0 = (rowTile & 15) * 64;  // row within tensor
    const int koff  = isEnc ? 0 : 256;
    const int d0    = colTile * 32;

    float acc[4][4] = {};

    const int quad = tid & 15;   // staging: float4 index within 64-float k-chunk

    for (int kc = 0; kc < 256; kc += TK) {
        // stage A tile: 64 rows x 64 k
        {
            const int rbase = tid >> 4;  // 0..7
            #pragma unroll
            for (int p = 0; p < 8; ++p) {
                const int r = rbase + p * 8;
                const float4 v = *(const float4*)&A[(arow0 + r) * 256 + kc + quad * 4];
                *(float4*)&As[r][quad * 4] = v;
            }
            // stage W tile: 32 d-rows x 64 k
            const int c0 = tid >> 4;  // 0..7
            #pragma unroll
            for (int p = 0; p < 4; ++p) {
                const int c = c0 + p * 8;
                const float4 v = *(const float4*)&W[(d0 + c) * 512 + koff + kc + quad * 4];
                *(float4*)&Ws[c][quad * 4] = v;
            }
        }
        __syncthreads();

        #pragma unroll 2
        for (int kk = 0; kk < TK; kk += 4) {
            float4 a[4], w[4];
            #pragma unroll
            for (int i = 0; i < 4; ++i) a[i] = *(float4*)&As[ty + i * 16][kk];
            #pragma unroll
            for (int j = 0; j < 4; ++j) w[j] = *(float4*)&Ws[tx + j * 8][kk];
            #pragma unroll
            for (int i = 0; i < 4; ++i)
                #pragma unroll
                for (int j = 0; j < 4; ++j) {
                    acc[i][j] += a[i].x * w[j].x;
                    acc[i][j] += a[i].y * w[j].y;
                    acc[i][j] += a[i].z * w[j].z;
                    acc[i][j] += a[i].w * w[j].w;
                }
        }
        __syncthreads();
    }

    float* __restrict__ out = isEnc ? epb : dp;
    #pragma unroll
    for (int i = 0; i < 4; ++i) {
        const int r = arow0 + ty + i * 16;
        #pragma unroll
        for (int j = 0; j < 4; ++j) {
            const int d = d0 + tx + j * 8;
            float v = acc[i][j];
            if (isEnc) v += bmlp[d];
            out[r * 256 + d] = v;
        }
    }
}

// ---------------- Kernel 2: fused relu-MLP attention scores ----------------
// NO LDS. Each thread computes a 2x2 (q,e) output tile; operand rows live in
// registers, loaded 32-h chunks at a time straight from global (L1/L2-hot:
// dp/epb total 2 MB, each row reused by 16 blocks). w_out reads are
// wave-uniform -> scalar s_load (SGPR operand, free). Inner loop = pure VALU:
// per h-quad 16x {add,max,fma}. 512 blocks x 256 thr = 2 waves/SIMD.
__global__ __launch_bounds__(256) void attn_kernel(
    const float* __restrict__ dp, const float* __restrict__ epb,
    const float* __restrict__ wout, const float* __restrict__ bout,
    float* __restrict__ out)
{
    const int tid = threadIdx.x;
    const int tx = tid & 15;        // e group: cols tx, tx+16
    const int ty = tid >> 4;        // q group: rows ty, ty+16
    const int et = blockIdx.x;      // 0..15
    const int qt = blockIdx.y;      // 0..15
    const int b  = blockIdx.z;      // 0..1
    const int q0 = b * 512 + qt * 32;
    const int e0 = b * 512 + et * 32;

    const float* __restrict__ dpr0 = dp  + (size_t)(q0 + ty) * 256;
    const float* __restrict__ dpr1 = dp  + (size_t)(q0 + ty + 16) * 256;
    const float* __restrict__ epr0 = epb + (size_t)(e0 + tx) * 256;
    const float* __restrict__ epr1 = epb + (size_t)(e0 + tx + 16) * 256;

    float acc00 = 0.f, acc01 = 0.f, acc10 = 0.f, acc11 = 0.f;

    #pragma unroll 1
    for (int hc = 0; hc < 256; hc += 32) {
        #pragma unroll
        for (int j = 0; j < 8; ++j) {
            const int h = hc + j * 4;
            const float4 a0 = *(const float4*)&dpr0[h];
            const float4 a1 = *(const float4*)&dpr1[h];
            const float4 b0 = *(const float4*)&epr0[h];
            const float4 b1 = *(const float4*)&epr1[h];
            const float4 w  = *(const float4*)&wout[h];   // uniform addr -> s_load

            #define MLP_STEP(c)                                 \
                acc00 += fmaxf(a0.c + b0.c, 0.f) * w.c;         \
                acc01 += fmaxf(a0.c + b1.c, 0.f) * w.c;         \
                acc10 += fmaxf(a1.c + b0.c, 0.f) * w.c;         \
                acc11 += fmaxf(a1.c + b1.c, 0.f) * w.c;
            MLP_STEP(x) MLP_STEP(y) MLP_STEP(z) MLP_STEP(w)
            #undef MLP_STEP
        }
    }

    const float bo = bout[0];
    const int qa = q0 + ty;             // global row (incl batch)
    const int ea = et * 32 + tx;        // col within batch
    float* __restrict__ orow0 = out + (size_t)qa * 512;
    float* __restrict__ orow1 = out + (size_t)(qa + 16) * 512;
    orow0[ea]      = acc00 + bo;
    orow0[ea + 16] = acc01 + bo;
    orow1[ea]      = acc10 + bo;
    orow1[ea + 16] = acc11 + bo;
}

extern "C" void kernel_launch(void* const* d_in, const int* in_sizes, int n_in,
                              void* d_out, int out_size, void* d_ws, size_t ws_size,
                              hipStream_t stream) {
    const float* dec  = (const float*)d_in[0];
    const float* enc  = (const float*)d_in[1];
    const float* W    = (const float*)d_in[2];
    const float* bmlp = (const float*)d_in[3];
    const float* wout = (const float*)d_in[4];
    const float* bout = (const float*)d_in[5];
    float* outp = (float*)d_out;

    float* dp  = (float*)d_ws;                 // 1024*256 f32 = 1 MB
    float* epb = dp + 1024 * 256;              // 1 MB

    proj_kernel<<<dim3(8, 32), 128, 0, stream>>>(dec, enc, W, bmlp, dp, epb);
    attn_kernel<<<dim3(16, 16, 2), 256, 0, stream>>>(dp, epb, wout, bout, outp);
}

// Round 3
// 104.134 us; speedup vs baseline: 1.1047x; 1.1047x over previous
//
#include <hip/hip_runtime.h>

// Problem: B=2, DEC=ENC=512, H=256.
// dec:(2,512,256) enc:(2,512,256) W:(256,512) b_mlp:(256) w_out:(1,256) b_out:(1)
// dp[r][d]  = sum_h dec[r][h]*W[d][256+h]            (r in 0..1023)
// epb[r][d] = sum_h enc[r][h]*W[d][h] + b_mlp[d]
// attn[b,q,e] = sum_h relu(dp[bq][h]+epb[be][h]) * w[h] + b_out
//
// Both kernels use the same structure: 64 lanes of a wave = 64 values of the
// "column-like" operand (staged in LDS, XOR-swizzled, one ds_read_b128 per
// 4-k per thread); each wave owns 4 rows of the other operand, which are
// WAVE-UNIFORM -> broadcast global loads (single cacheline per instr, L2-hot).
// 512 blocks x 256 thr = 8 waves/CU; VGPR cap 256 via launch_bounds(256,2).

#define SWZ(row, u) ((u) ^ ((row) & 7))   // 16B-unit XOR swizzle, stride 256 f32

// ---------------- Kernel 1: fused projections ----------------
// Block: 16 output rows x 64 d-cols. W-tile (64 d-rows x 256 k) in LDS.
// grid (4 dTiles, 128 rowTiles); rowTiles 0..63 = dec, 64..127 = enc.
__global__ __launch_bounds__(256, 2) void proj_kernel(
    const float* __restrict__ dec, const float* __restrict__ enc,
    const float* __restrict__ W, const float* __restrict__ bmlp,
    float* __restrict__ dp, float* __restrict__ epb)
{
    __shared__ float wS[64 * 256];   // 64 KB

    const int tid  = threadIdx.x;
    const int lane = tid & 63;       // d within tile
    const int wr   = tid >> 6;       // wave id: row group
    const int dT   = blockIdx.x;     // 0..3
    const int rT   = blockIdx.y;     // 0..127
    const bool isEnc = rT >= 64;
    const float* __restrict__ A = isEnc ? enc : dec;
    const int koff  = isEnc ? 0 : 256;
    const int d0    = dT * 64;
    const int arow0 = (rT & 63) * 16;

    // stage W tile (swizzled): thread s*256+tid -> row idx>>6, unit idx&63
    #pragma unroll
    for (int s = 0; s < 16; ++s) {
        const int idx = s * 256 + tid;
        const int r   = idx >> 6;
        const int u   = idx & 63;
        const float4 v = *(const float4*)&W[(d0 + r) * 512 + koff + u * 4];
        *(float4*)&wS[r * 256 + SWZ(r, u) * 4] = v;
    }
    __syncthreads();

    const float* __restrict__ Ar = A + (size_t)(arow0 + wr * 4) * 256;
    float acc0 = 0.f, acc1 = 0.f, acc2 = 0.f, acc3 = 0.f;

    #pragma unroll 4
    for (int hq = 0; hq < 64; ++hq) {
        const float4 wv = *(const float4*)&wS[lane * 256 + SWZ(lane, hq) * 4];
        const float4 a0 = *(const float4*)&Ar[0 * 256 + hq * 4];   // wave-uniform
        const float4 a1 = *(const float4*)&Ar[1 * 256 + hq * 4];
        const float4 a2 = *(const float4*)&Ar[2 * 256 + hq * 4];
        const float4 a3 = *(const float4*)&Ar[3 * 256 + hq * 4];
        #define K1_STEP(c) \
            acc0 += a0.c * wv.c; acc1 += a1.c * wv.c; \
            acc2 += a2.c * wv.c; acc3 += a3.c * wv.c;
        K1_STEP(x) K1_STEP(y) K1_STEP(z) K1_STEP(w)
        #undef K1_STEP
    }

    float* __restrict__ outp = isEnc ? epb : dp;
    const int row = arow0 + wr * 4;
    const int d   = d0 + lane;
    const float bias = isEnc ? bmlp[d] : 0.f;
    outp[(size_t)(row + 0) * 256 + d] = acc0 + bias;
    outp[(size_t)(row + 1) * 256 + d] = acc1 + bias;
    outp[(size_t)(row + 2) * 256 + d] = acc2 + bias;
    outp[(size_t)(row + 3) * 256 + d] = acc3 + bias;
}

// ---------------- Kernel 2: fused relu-MLP attention scores ----------------
// Block: 16 q-rows x 64 e-cols. ep-tile (64 e-rows x 256 h) in LDS swizzled.
// Each wave: 4 q-rows (uniform, broadcast loads), lane = e. grid (8,32,2).
__global__ __launch_bounds__(256, 2) void attn_kernel(
    const float* __restrict__ dp, const float* __restrict__ epb,
    const float* __restrict__ wout, const float* __restrict__ bout,
    float* __restrict__ out)
{
    __shared__ float eS[64 * 256];   // 64 KB

    const int tid  = threadIdx.x;
    const int lane = tid & 63;       // e within tile
    const int wq   = tid >> 6;       // wave id: q group
    const int eT   = blockIdx.x;     // 0..7
    const int qT   = blockIdx.y;     // 0..31
    const int b    = blockIdx.z;     // 0..1
    const int e0g  = b * 512 + eT * 64;
    const int q0   = b * 512 + qT * 16 + wq * 4;   // global row incl. batch

    // stage ep tile (swizzled)
    #pragma unroll
    for (int s = 0; s < 16; ++s) {
        const int idx = s * 256 + tid;
        const int r   = idx >> 6;
        const int u   = idx & 63;
        const float4 v = *(const float4*)&epb[(size_t)(e0g + r) * 256 + u * 4];
        *(float4*)&eS[r * 256 + SWZ(r, u) * 4] = v;
    }
    __syncthreads();

    const float* __restrict__ dpr = dp + (size_t)q0 * 256;
    float acc0 = 0.f, acc1 = 0.f, acc2 = 0.f, acc3 = 0.f;

    #pragma unroll 4
    for (int hq = 0; hq < 64; ++hq) {
        const float4 ev = *(const float4*)&eS[lane * 256 + SWZ(lane, hq) * 4];
        const float4 wv = *(const float4*)&wout[hq * 4];           // wave-uniform
        const float4 d0v = *(const float4*)&dpr[0 * 256 + hq * 4]; // wave-uniform
        const float4 d1v = *(const float4*)&dpr[1 * 256 + hq * 4];
        const float4 d2v = *(const float4*)&dpr[2 * 256 + hq * 4];
        const float4 d3v = *(const float4*)&dpr[3 * 256 + hq * 4];
        #define K2_STEP(c) \
            acc0 += fmaxf(d0v.c + ev.c, 0.f) * wv.c; \
            acc1 += fmaxf(d1v.c + ev.c, 0.f) * wv.c; \
            acc2 += fmaxf(d2v.c + ev.c, 0.f) * wv.c; \
            acc3 += fmaxf(d3v.c + ev.c, 0.f) * wv.c;
        K2_STEP(x) K2_STEP(y) K2_STEP(z) K2_STEP(w)
        #undef K2_STEP
    }

    const float bo = bout[0];
    const int col = eT * 64 + lane;       // e within batch
    out[(size_t)(q0 + 0) * 512 + col] = acc0 + bo;
    out[(size_t)(q0 + 1) * 512 + col] = acc1 + bo;
    out[(size_t)(q0 + 2) * 512 + col] = acc2 + bo;
    out[(size_t)(q0 + 3) * 512 + col] = acc3 + bo;
}

extern "C" void kernel_launch(void* const* d_in, const int* in_sizes, int n_in,
                              void* d_out, int out_size, void* d_ws, size_t ws_size,
                              hipStream_t stream) {
    const float* dec  = (const float*)d_in[0];
    const float* enc  = (const float*)d_in[1];
    const float* W    = (const float*)d_in[2];
    const float* bmlp = (const float*)d_in[3];
    const float* wout = (const float*)d_in[4];
    const float* bout = (const float*)d_in[5];
    float* outp = (float*)d_out;

    float* dp  = (float*)d_ws;                 // 1024*256 f32 = 1 MB
    float* epb = dp + 1024 * 256;              // 1 MB

    proj_kernel<<<dim3(4, 128), 256, 0, stream>>>(dec, enc, W, bmlp, dp, epb);
    attn_kernel<<<dim3(8, 32, 2), 256, 0, stream>>>(dp, epb, wout, bout, outp);
}

// Round 4
// 94.819 us; speedup vs baseline: 1.2132x; 1.0982x over previous
//
#include <hip/hip_runtime.h>

// Problem: B=2, DEC=ENC=512, H=256.
// dec:(2,512,256) enc:(2,512,256) W:(256,512) b_mlp:(256) w_out:(1,256) b_out:(1)
// dp[r][d]  = sum_h dec[r][h]*W[d][256+h]            (r in 0..1023)
// epb[r][d] = sum_h enc[r][h]*W[d][h] + b_mlp[d]
// attn[b,q,e] = sum_h relu(dp[bq][h]+epb[be][h]) * w[h] + b_out

#define SWZ(row, u) ((u) ^ ((row) & 7))   // 16B-unit XOR swizzle

// ---------------- Kernel 1: fused projections (unchanged from R3) ----------------
// Block: 16 output rows x 64 d-cols. W-tile (64 d-rows x 256 k) in LDS swizzled.
// grid (4 dTiles, 128 rowTiles); rowTiles 0..63 = dec, 64..127 = enc.
__global__ __launch_bounds__(256, 2) void proj_kernel(
    const float* __restrict__ dec, const float* __restrict__ enc,
    const float* __restrict__ W, const float* __restrict__ bmlp,
    float* __restrict__ dp, float* __restrict__ epb)
{
    __shared__ float wS[64 * 256];   // 64 KB

    const int tid  = threadIdx.x;
    const int lane = tid & 63;       // d within tile
    const int wr   = tid >> 6;       // wave id: row group
    const int dT   = blockIdx.x;     // 0..3
    const int rT   = blockIdx.y;     // 0..127
    const bool isEnc = rT >= 64;
    const float* __restrict__ A = isEnc ? enc : dec;
    const int koff  = isEnc ? 0 : 256;
    const int d0    = dT * 64;
    const int arow0 = (rT & 63) * 16;

    #pragma unroll
    for (int s = 0; s < 16; ++s) {
        const int idx = s * 256 + tid;
        const int r   = idx >> 6;
        const int u   = idx & 63;
        const float4 v = *(const float4*)&W[(d0 + r) * 512 + koff + u * 4];
        *(float4*)&wS[r * 256 + SWZ(r, u) * 4] = v;
    }
    __syncthreads();

    const float* __restrict__ Ar = A + (size_t)(arow0 + wr * 4) * 256;
    float acc0 = 0.f, acc1 = 0.f, acc2 = 0.f, acc3 = 0.f;

    #pragma unroll 4
    for (int hq = 0; hq < 64; ++hq) {
        const float4 wv = *(const float4*)&wS[lane * 256 + SWZ(lane, hq) * 4];
        const float4 a0 = *(const float4*)&Ar[0 * 256 + hq * 4];   // wave-uniform
        const float4 a1 = *(const float4*)&Ar[1 * 256 + hq * 4];
        const float4 a2 = *(const float4*)&Ar[2 * 256 + hq * 4];
        const float4 a3 = *(const float4*)&Ar[3 * 256 + hq * 4];
        #define K1_STEP(c) \
            acc0 += a0.c * wv.c; acc1 += a1.c * wv.c; \
            acc2 += a2.c * wv.c; acc3 += a3.c * wv.c;
        K1_STEP(x) K1_STEP(y) K1_STEP(z) K1_STEP(w)
        #undef K1_STEP
    }

    float* __restrict__ outp = isEnc ? epb : dp;
    const int row = arow0 + wr * 4;
    const int d   = d0 + lane;
    const float bias = isEnc ? bmlp[d] : 0.f;
    outp[(size_t)(row + 0) * 256 + d] = acc0 + bias;
    outp[(size_t)(row + 1) * 256 + d] = acc1 + bias;
    outp[(size_t)(row + 2) * 256 + d] = acc2 + bias;
    outp[(size_t)(row + 3) * 256 + d] = acc3 + bias;
}

// ---------------- Kernel 2: fused relu-MLP attention scores ----------------
// Block: 16 q x 32 e. ALL operands in LDS -> zero in-loop VMEM.
//   eS: 32 e-rows x 256 h, XOR-swizzled (lane-distinct reads, conflict-optimal)
//   dS: 16 q-rows x 256 h, linear (row-uniform reads -> broadcast)
//   wS: 256 h (broadcast)
// Wave layout: e = lane&31, h-half = lane>>5 (h in hh*128..+127).
// Wave wq owns q rows wq*4+r (r=0..3). Final: __shfl_xor(acc,32) combines
// the two h-halves; lanes 0..31 store. 1024 blocks, 256 thr, 49.25 KB LDS
// -> 3 blocks/CU, VALU-bound inner loop (48 VALU : 6 LDS per h-quad).
__global__ __launch_bounds__(256, 2) void attn_kernel(
    const float* __restrict__ dp, const float* __restrict__ epb,
    const float* __restrict__ wout, const float* __restrict__ bout,
    float* __restrict__ out)
{
    __shared__ float eS[32 * 256];   // 32 KB
    __shared__ float dS[16 * 256];   // 16 KB
    __shared__ float wS[256];        // 1 KB

    const int tid  = threadIdx.x;
    const int lane = tid & 63;
    const int wq   = tid >> 6;       // 0..3: q group
    const int e    = lane & 31;      // e within tile
    const int hh   = lane >> 5;      // h half: 0 or 1
    const int eT   = blockIdx.x;     // 0..15
    const int qT   = blockIdx.y;     // 0..31
    const int b    = blockIdx.z;     // 0..1
    const int e0g  = b * 512 + eT * 32;
    const int q0g  = b * 512 + qT * 16;

    // stage ep tile (swizzled): 32 rows, 8 float4/thread
    #pragma unroll
    for (int s = 0; s < 8; ++s) {
        const int idx = s * 256 + tid;
        const int r   = idx >> 6;
        const int u   = idx & 63;
        const float4 v = *(const float4*)&epb[(size_t)(e0g + r) * 256 + u * 4];
        *(float4*)&eS[r * 256 + SWZ(r, u) * 4] = v;
    }
    // stage dp tile (linear): 16 rows, 4 float4/thread
    #pragma unroll
    for (int s = 0; s < 4; ++s) {
        const int idx = s * 256 + tid;
        const int r   = idx >> 6;
        const int u   = idx & 63;
        *(float4*)&dS[r * 256 + u * 4] =
            *(const float4*)&dp[(size_t)(q0g + r) * 256 + u * 4];
    }
    if (tid < 64) *(float4*)&wS[tid * 4] = *(const float4*)&wout[tid * 4];
    __syncthreads();

    float acc0 = 0.f, acc1 = 0.f, acc2 = 0.f, acc3 = 0.f;
    const int ub = hh * 32;          // base 16B-unit of this lane's h-half

    #pragma unroll 4
    for (int hq = 0; hq < 32; ++hq) {
        const float4 ev = *(const float4*)&eS[e * 256 + SWZ(e, ub + hq) * 4];
        const float4 wv = *(const float4*)&wS[(ub + hq) * 4];
        const float4 d0v = *(const float4*)&dS[(wq * 4 + 0) * 256 + (ub + hq) * 4];
        const float4 d1v = *(const float4*)&dS[(wq * 4 + 1) * 256 + (ub + hq) * 4];
        const float4 d2v = *(const float4*)&dS[(wq * 4 + 2) * 256 + (ub + hq) * 4];
        const float4 d3v = *(const float4*)&dS[(wq * 4 + 3) * 256 + (ub + hq) * 4];
        #define K2_STEP(c) \
            acc0 += fmaxf(d0v.c + ev.c, 0.f) * wv.c; \
            acc1 += fmaxf(d1v.c + ev.c, 0.f) * wv.c; \
            acc2 += fmaxf(d2v.c + ev.c, 0.f) * wv.c; \
            acc3 += fmaxf(d3v.c + ev.c, 0.f) * wv.c;
        K2_STEP(x) K2_STEP(y) K2_STEP(z) K2_STEP(w)
        #undef K2_STEP
    }

    // combine h-halves (partner lane differs only in bit 5)
    acc0 += __shfl_xor(acc0, 32);
    acc1 += __shfl_xor(acc1, 32);
    acc2 += __shfl_xor(acc2, 32);
    acc3 += __shfl_xor(acc3, 32);

    if (hh == 0) {
        const float bo = bout[0];
        const int row = q0g + wq * 4;
        const int col = eT * 32 + e;         // e within batch
        out[(size_t)(row + 0) * 512 + col] = acc0 + bo;
        out[(size_t)(row + 1) * 512 + col] = acc1 + bo;
        out[(size_t)(row + 2) * 512 + col] = acc2 + bo;
        out[(size_t)(row + 3) * 512 + col] = acc3 + bo;
    }
}

extern "C" void kernel_launch(void* const* d_in, const int* in_sizes, int n_in,
                              void* d_out, int out_size, void* d_ws, size_t ws_size,
                              hipStream_t stream) {
    const float* dec  = (const float*)d_in[0];
    const float* enc  = (const float*)d_in[1];
    const float* W    = (const float*)d_in[2];
    const float* bmlp = (const float*)d_in[3];
    const float* wout = (const float*)d_in[4];
    const float* bout = (const float*)d_in[5];
    float* outp = (float*)d_out;

    float* dp  = (float*)d_ws;                 // 1024*256 f32 = 1 MB
    float* epb = dp + 1024 * 256;              // 1 MB

    proj_kernel<<<dim3(4, 128), 256, 0, stream>>>(dec, enc, W, bmlp, dp, epb);
    attn_kernel<<<dim3(16, 32, 2), 256, 0, stream>>>(dp, epb, wout, bout, outp);
}

// Round 5
// 89.721 us; speedup vs baseline: 1.2822x; 1.0568x over previous
//
#include <hip/hip_runtime.h>

// Problem: B=2, DEC=ENC=512, H=256.
// dec:(2,512,256) enc:(2,512,256) W:(256,512) b_mlp:(256) w_out:(1,256) b_out:(1)
// dp[r][d]  = sum_h dec[r][h]*W[d][256+h]            (r in 0..1023)
// epb[r][d] = sum_h enc[r][h]*W[d][h] + b_mlp[d]
// attn[b,q,e] = sum_h relu(dp[bq][h]+epb[be][h]) * w[h] + b_out
//
// K1 computes projections in f32, stores them as f16 (rel eps 2^-11; final
// tolerance 1.87e-2 leaves ~5x margin). K2 consumes f16 tiles with packed
// math: v_pk_add_f16 + v_pk_max_f16 + v_dot2_f32_f16 (f32 accumulate) =
// 3 instrs per 2 h-elements, half the f32-scalar VALU cost.

typedef _Float16 h2 __attribute__((ext_vector_type(2)));

#define SWZ(row, u) ((u) ^ ((row) & 7))   // 16B-unit XOR swizzle

static __device__ inline float dot2acc(h2 a, h2 b, float c) {
#if defined(__has_builtin) && __has_builtin(__builtin_amdgcn_fdot2)
    return __builtin_amdgcn_fdot2(a, b, c, false);   // v_dot2_f32_f16
#else
    return c + (float)a[0] * (float)b[0] + (float)a[1] * (float)b[1];
#endif
}

// ---------------- Kernel 1: fused projections (f32 compute, f16 store) ----------------
// Block: 16 output rows x 64 d-cols. W-tile (64 d-rows x 256 k) in LDS swizzled.
// grid (4 dTiles, 128 rowTiles); rowTiles 0..63 = dec, 64..127 = enc.
__global__ __launch_bounds__(256, 2) void proj_kernel(
    const float* __restrict__ dec, const float* __restrict__ enc,
    const float* __restrict__ W, const float* __restrict__ bmlp,
    _Float16* __restrict__ dp, _Float16* __restrict__ epb)
{
    __shared__ float wS[64 * 256];   // 64 KB

    const int tid  = threadIdx.x;
    const int lane = tid & 63;       // d within tile
    const int wr   = tid >> 6;       // wave id: row group
    const int dT   = blockIdx.x;     // 0..3
    const int rT   = blockIdx.y;     // 0..127
    const bool isEnc = rT >= 64;
    const float* __restrict__ A = isEnc ? enc : dec;
    const int koff  = isEnc ? 0 : 256;
    const int d0    = dT * 64;
    const int arow0 = (rT & 63) * 16;

    #pragma unroll
    for (int s = 0; s < 16; ++s) {
        const int idx = s * 256 + tid;
        const int r   = idx >> 6;
        const int u   = idx & 63;
        const float4 v = *(const float4*)&W[(d0 + r) * 512 + koff + u * 4];
        *(float4*)&wS[r * 256 + SWZ(r, u) * 4] = v;
    }
    __syncthreads();

    const float* __restrict__ Ar = A + (size_t)(arow0 + wr * 4) * 256;
    float acc0 = 0.f, acc1 = 0.f, acc2 = 0.f, acc3 = 0.f;

    #pragma unroll 4
    for (int hq = 0; hq < 64; ++hq) {
        const float4 wv = *(const float4*)&wS[lane * 256 + SWZ(lane, hq) * 4];
        const float4 a0 = *(const float4*)&Ar[0 * 256 + hq * 4];   // wave-uniform
        const float4 a1 = *(const float4*)&Ar[1 * 256 + hq * 4];
        const float4 a2 = *(const float4*)&Ar[2 * 256 + hq * 4];
        const float4 a3 = *(const float4*)&Ar[3 * 256 + hq * 4];
        #define K1_STEP(c) \
            acc0 += a0.c * wv.c; acc1 += a1.c * wv.c; \
            acc2 += a2.c * wv.c; acc3 += a3.c * wv.c;
        K1_STEP(x) K1_STEP(y) K1_STEP(z) K1_STEP(w)
        #undef K1_STEP
    }

    _Float16* __restrict__ outp = isEnc ? epb : dp;
    const int row = arow0 + wr * 4;
    const int d   = d0 + lane;
    const float bias = isEnc ? bmlp[d] : 0.f;
    outp[(size_t)(row + 0) * 256 + d] = (_Float16)(acc0 + bias);
    outp[(size_t)(row + 1) * 256 + d] = (_Float16)(acc1 + bias);
    outp[(size_t)(row + 2) * 256 + d] = (_Float16)(acc2 + bias);
    outp[(size_t)(row + 3) * 256 + d] = (_Float16)(acc3 + bias);
}

// ---------------- Kernel 2: fused relu-MLP attention scores (packed f16) ----------------
// Block: 32 q x 32 e, 4 waves, each wave owns 8 q-rows. Lane = (e = lane&31,
// h-half hh = lane>>5); each lane covers 128 h of its half in 16 chunks of 8.
//   eS: 32 e-rows x 256 h f16, XOR-swizzled -> lane-distinct b128 reads, conflict-free
//   dS: 32 q-rows x 256 h f16, linear -> 2-address broadcast reads (free)
//   wS: 256 h f16 (broadcast)
// Inner: per 8h per q-row: 4 pk_add + 4 pk_max + 4 dot2 (f32 acc).
// Final: __shfl_xor(acc,32) combines halves; lanes hh==0 store.
// 512 blocks x 256 thr, 33 KB LDS -> 2 blocks/CU resident, 8 waves/CU.
__global__ __launch_bounds__(256, 2) void attn_kernel(
    const _Float16* __restrict__ dp, const _Float16* __restrict__ epb,
    const float* __restrict__ wout, const float* __restrict__ bout,
    float* __restrict__ out)
{
    __shared__ __align__(16) _Float16 eS[32 * 256];   // 16 KB
    __shared__ __align__(16) _Float16 dS[32 * 256];   // 16 KB
    __shared__ __align__(16) _Float16 wS[256];        // 0.5 KB

    const int tid  = threadIdx.x;
    const int lane = tid & 63;
    const int wq   = tid >> 6;       // 0..3: q group (8 rows each)
    const int e    = lane & 31;      // e within tile
    const int hh   = lane >> 5;      // h half: 0 or 1
    const int eT   = blockIdx.x;     // 0..15
    const int qT   = blockIdx.y;     // 0..15
    const int b    = blockIdx.z;     // 0..1
    const int e0g  = b * 512 + eT * 32;
    const int q0g  = b * 512 + qT * 32;

    // stage eS (swizzled) and dS (linear): 32 rows x 32 16B-units each
    #pragma unroll
    for (int s = 0; s < 4; ++s) {
        const int idx = s * 256 + tid;
        const int r   = idx >> 5;
        const int u   = idx & 31;
        const float4 ev = *(const float4*)&epb[(size_t)(e0g + r) * 256 + u * 8];
        *(float4*)&eS[r * 256 + SWZ(r, u) * 8] = ev;
        const float4 dv = *(const float4*)&dp[(size_t)(q0g + r) * 256 + u * 8];
        *(float4*)&dS[r * 256 + u * 8] = dv;
    }
    if (tid < 32) {   // convert w_out f32 -> f16, 8 h per thread
        const float4 w0 = *(const float4*)&wout[tid * 8];
        const float4 w1 = *(const float4*)&wout[tid * 8 + 4];
        h2 hw[4];
        hw[0] = h2{(_Float16)w0.x, (_Float16)w0.y};
        hw[1] = h2{(_Float16)w0.z, (_Float16)w0.w};
        hw[2] = h2{(_Float16)w1.x, (_Float16)w1.y};
        hw[3] = h2{(_Float16)w1.z, (_Float16)w1.w};
        *(float4*)&wS[tid * 8] = *(const float4*)hw;
    }
    __syncthreads();

    float acc[8] = {0.f, 0.f, 0.f, 0.f, 0.f, 0.f, 0.f, 0.f};
    const h2 zero = h2{(_Float16)0, (_Float16)0};
    const int qb = wq * 8;

    #pragma unroll 2
    for (int it = 0; it < 16; ++it) {
        const int uu = hh * 16 + it;                       // this lane's 16B unit
        const float4 eraw = *(const float4*)&eS[e * 256 + SWZ(e, uu) * 8];
        const float4 wraw = *(const float4*)&wS[uu * 8];
        const h2* ep2 = (const h2*)&eraw;
        const h2* wp2 = (const h2*)&wraw;
        #pragma unroll
        for (int r = 0; r < 8; ++r) {
            const float4 draw = *(const float4*)&dS[(qb + r) * 256 + uu * 8];
            const h2* dp2 = (const h2*)&draw;
            #pragma unroll
            for (int c = 0; c < 4; ++c) {
                h2 x = dp2[c] + ep2[c];                    // v_pk_add_f16
                x = __builtin_elementwise_max(x, zero);    // v_pk_max_f16
                acc[r] = dot2acc(x, wp2[c], acc[r]);       // v_dot2_f32_f16
            }
        }
    }

    // combine h-halves (partner differs only in lane bit 5)
    #pragma unroll
    for (int r = 0; r < 8; ++r) acc[r] += __shfl_xor(acc[r], 32);

    if (hh == 0) {
        const float bo = bout[0];
        const int col = eT * 32 + e;          // e within batch
        #pragma unroll
        for (int r = 0; r < 8; ++r)
            out[(size_t)(q0g + qb + r) * 512 + col] = acc[r] + bo;
    }
}

extern "C" void kernel_launch(void* const* d_in, const int* in_sizes, int n_in,
                              void* d_out, int out_size, void* d_ws, size_t ws_size,
                              hipStream_t stream) {
    const float* dec  = (const float*)d_in[0];
    const float* enc  = (const float*)d_in[1];
    const float* W    = (const float*)d_in[2];
    const float* bmlp = (const float*)d_in[3];
    const float* wout = (const float*)d_in[4];
    const float* bout = (const float*)d_in[5];
    float* outp = (float*)d_out;

    _Float16* dp16  = (_Float16*)d_ws;          // 1024*256 f16 = 512 KB
    _Float16* epb16 = dp16 + 1024 * 256;        // 512 KB

    proj_kernel<<<dim3(4, 128), 256, 0, stream>>>(dec, enc, W, bmlp, dp16, epb16);
    attn_kernel<<<dim3(16, 16, 2), 256, 0, stream>>>(dp16, epb16, wout, bout, outp);
}